// Round 13
// baseline (1360.629 us; speedup 1.0000x reference)
//
#include <hip/hip_runtime.h>
#include <hip/hip_fp16.h>

// HGNN aggregation: out = x + segment_sum(x[src_idx], dst_idx)
// x: [100000, 128] f32; src_idx/dst_idx: [2,000,000] int32.
//
// Round 13: dimension-split aggregate -> L2-resident gather.
//   1. memset cursors
//   2. static fused prep: partition into per-bucket arenas || f16 convert
//   3. aggregate: block = (bucket, dimgroup g=blockIdx&7). XCD round-robin
//      dispatch parks dimgroup g on XCD g -> each XCD re-reads ONLY its
//      3.2 MB mirror slice (L2-resident). 4 lanes x 8B per edge, LDS f32
//      accumulator [128][16] (stride 17 vs bank conflicts) via ds_add_f32,
//      writeout = exact 64B lines with f32 residual.
//   4. spill_apply: f32 atomics for overflow (expected 0).

constexpr int DIM = 128;
constexpr int BSHIFT = 7;            // 128 nodes per bucket
constexpr int GNODES = 1 << BSHIFT;  // 128
constexpr int MAXB = 1024;           // max buckets (N <= 131072)
constexpr int CE = 8192;             // edges per partition chunk
constexpr int CAP_MAX = 3072;        // arena slots per bucket
constexpr int ASTRIDE = 17;          // padded LDS accum row stride (banks)

__global__ void hgnn_fused_prep(const float4* __restrict__ x4,
                                ushort4* __restrict__ xh4, int n4,
                                const int* __restrict__ src,
                                const int* __restrict__ dst,
                                int* __restrict__ cursor,
                                int* __restrict__ arena, int cap,
                                int* __restrict__ spillCnt,
                                int2* __restrict__ spill, int spillCap,
                                int nedges, int nbk, int nPart) {
    __shared__ int h[MAXB];
    __shared__ int lb[MAXB];
    const int tid = threadIdx.x;

    if ((int)blockIdx.x < nPart) {
        // ---- partition path ----
        int c0 = blockIdx.x * CE;
        int c1 = min(c0 + CE, nedges);
        for (int i = tid; i < nbk; i += blockDim.x) h[i] = 0;
        __syncthreads();
        for (int i = c0 + tid; i < c1; i += blockDim.x)
            atomicAdd(&h[dst[i] >> BSHIFT], 1);
        __syncthreads();
        for (int i = tid; i < nbk; i += blockDim.x)
            lb[i] = h[i] ? atomicAdd(&cursor[i], h[i]) : 0;
        __syncthreads();
        for (int i = c0 + tid; i < c1; i += blockDim.x) {
            int s = src[i];
            int d = dst[i];
            int bk = d >> BSHIFT;
            int pos = atomicAdd(&lb[bk], 1);
            if (pos < cap) {
                arena[(size_t)bk * cap + pos] = s | ((d & (GNODES - 1)) << 17);
            } else {
                int sp = atomicAdd(spillCnt, 1);
                if (sp < spillCap) spill[sp] = make_int2(s, d);
            }
        }
    } else {
        // ---- convert path (concurrent with partition) ----
        int bid = blockIdx.x - nPart;
        int nconv = gridDim.x - nPart;
        int i = bid * blockDim.x + tid;
        int stride = nconv * blockDim.x;
        for (int k = i; k < n4; k += stride) {
            float4 v = x4[k];
            ushort4 o;
            o.x = __half_as_ushort(__float2half_rn(v.x));
            o.y = __half_as_ushort(__float2half_rn(v.y));
            o.z = __half_as_ushort(__float2half_rn(v.z));
            o.w = __half_as_ushort(__float2half_rn(v.w));
            xh4[k] = o;
        }
    }
}

// block = (bucket b, dimgroup g). Processes ALL edges of bucket b for the
// 16 dims [g*16, g*16+16). LDS f32 accumulation, no sorting.
__global__ void hgnn_aggregate_dsplit(const float4* __restrict__ x4,
                                      const uint2* __restrict__ xh2,
                                      const int* __restrict__ arena, int cap,
                                      const int* __restrict__ cursor,
                                      float4* __restrict__ out4, int nnodes) {
    __shared__ float accum[GNODES * ASTRIDE];   // 8.7 KB
    const int b = blockIdx.x >> 3;
    const int g = blockIdx.x & 7;      // aligns with XCD round-robin
    const int tid = threadIdx.x;

    for (int i = tid; i < GNODES * ASTRIDE; i += 256) accum[i] = 0.f;
    __syncthreads();

    int cnt = cursor[b];
    if (cnt > cap) cnt = cap;
    const int* ar = arena + (size_t)b * cap;

    // 4 lanes per edge; each lane owns 8 B (4 f16 dims) of the 32 B slice
    const int sub = tid & 3;
    for (int i = (tid >> 2); i < cnt; i += 64) {
        int p = ar[i];
        int s = p & 0x1FFFF;
        int dl = p >> 17;
        uint2 v = xh2[(size_t)s * 32 + g * 4 + sub];
        __half2 hlo = *reinterpret_cast<const __half2*>(&v.x);
        __half2 hhi = *reinterpret_cast<const __half2*>(&v.y);
        float2 flo = __half22float2(hlo);
        float2 fhi = __half22float2(hhi);
        float* a = &accum[dl * ASTRIDE + sub * 4];
        atomicAdd(a + 0, flo.x);
        atomicAdd(a + 1, flo.y);
        atomicAdd(a + 2, fhi.x);
        atomicAdd(a + 3, fhi.y);
    }
    __syncthreads();

    // writeout: thread t -> node t>>1, half (t&1): dims g*16+half*8..+8
    // out byte addr = node*512 + g*64 + half*32  (full 64B lines per node)
    {
        int r = tid >> 1;
        int half = tid & 1;
        int node = (b << BSHIFT) + r;
        if (node < nnodes) {
            size_t o = (size_t)node * 32 + g * 4 + half * 2;
            float4 xa = x4[o];
            float4 xb = x4[o + 1];
            const float* a = &accum[r * ASTRIDE + half * 8];
            out4[o] = make_float4(xa.x + a[0], xa.y + a[1],
                                  xa.z + a[2], xa.w + a[3]);
            out4[o + 1] = make_float4(xb.x + a[4], xb.y + a[5],
                                      xb.z + a[6], xb.w + a[7]);
        }
    }
}

// handles overflow edges (expected none on this data); exact f32 path
__global__ void hgnn_spill_apply(const float4* __restrict__ x4,
                                 const int* __restrict__ spillCnt,
                                 const int2* __restrict__ spill,
                                 float* __restrict__ out, int spillCap) {
    int n = *spillCnt;
    if (n > spillCap) n = spillCap;
    int i = blockIdx.x * blockDim.x + threadIdx.x;
    int stride = gridDim.x * blockDim.x;
    for (int k = i; k < n * 32; k += stride) {
        int e = k >> 5;
        int cc = k & 31;
        int2 sd = spill[e];
        float4 v = x4[(size_t)sd.x * 32 + cc];
        float* o = out + (size_t)sd.y * DIM + cc * 4;
        atomicAdd(o + 0, v.x);
        atomicAdd(o + 1, v.y);
        atomicAdd(o + 2, v.z);
        atomicAdd(o + 3, v.w);
    }
}

static inline size_t align256(size_t v) { return (v + 255) & ~(size_t)255; }

extern "C" void kernel_launch(void* const* d_in, const int* in_sizes, int n_in,
                              void* d_out, int out_size, void* d_ws, size_t ws_size,
                              hipStream_t stream) {
    const float* x = (const float*)d_in[0];
    const int* src = (const int*)d_in[1];
    const int* dst = (const int*)d_in[2];
    float* out = (float*)d_out;

    const int E = in_sizes[1];                   // 2,000,000
    const int N = in_sizes[0] / DIM;             // 100,000
    const int n4 = N * (DIM / 4);                // 3.2M float4
    const int NBK = (N + GNODES - 1) >> BSHIFT;  // 782
    const int nPart = (E + CE - 1) / CE;         // 245 partition chunks

    // workspace: cursor[MAXB] + spillCnt | f16 mirror | arena | spill
    char* w = (char*)d_ws;
    size_t curBytes = align256((size_t)(MAXB + 1) * sizeof(int));
    size_t xhBytes = align256((size_t)N * DIM * 2);   // 25.6 MB
    size_t fixedBytes = curBytes + xhBytes;
    size_t spillReserve = 256 * 1024;

    size_t avail = (ws_size > fixedBytes + spillReserve)
                       ? (ws_size - fixedBytes - spillReserve) : 0;
    int cap = (int)((avail / sizeof(int)) / (size_t)NBK);
    if (cap > CAP_MAX) cap = CAP_MAX;
    if (cap < 64) cap = 64;    // degenerate ws; spill net keeps correctness

    int* cursor = (int*)w;                        // [NBK]
    int* spillCnt = cursor + MAXB;                // [1]
    ushort* xh = (ushort*)(w + curBytes);         // [N*128] f16
    int* arena = (int*)(w + fixedBytes);          // [NBK*cap]
    size_t arenaBytes = align256((size_t)NBK * cap * sizeof(int));
    int2* spill = (int2*)(w + fixedBytes + arenaBytes);
    int spillCap = (int)((ws_size > fixedBytes + arenaBytes)
                             ? (ws_size - fixedBytes - arenaBytes) / sizeof(int2)
                             : 0);

    // 1) zero cursors + spill counter
    (void)hipMemsetAsync(cursor, 0, (size_t)(MAXB + 1) * sizeof(int), stream);

    // 2) static fused: partition (blocks 0..nPart) || f16 convert (rest)
    {
        int grid = nPart + 1792;
        hipLaunchKernelGGL(hgnn_fused_prep, dim3(grid), dim3(256), 0, stream,
                           (const float4*)x, (ushort4*)xh, n4,
                           src, dst, cursor, arena, cap,
                           spillCnt, spill, spillCap, E, NBK, nPart);
    }

    // 3) dim-split aggregate: 8 dimgroups x NBK buckets
    hipLaunchKernelGGL(hgnn_aggregate_dsplit, dim3(NBK * 8), dim3(256), 0, stream,
                       (const float4*)x, (const uint2*)xh, arena, cap,
                       cursor, (float4*)out, N);

    // 4) apply spilled edges (normally zero work)
    hipLaunchKernelGGL(hgnn_spill_apply, dim3(64), dim3(256), 0, stream,
                       (const float4*)x, spillCnt, spill, out, spillCap);
}

// Round 14
// 1359.011 us; speedup vs baseline: 1.0012x; 1.0012x over previous
//
#include <hip/hip_runtime.h>
#include <hip/hip_fp16.h>

// HGNN aggregation: out = x + segment_sum(x[src_idx], dst_idx)
// x: [100000, 128] f32; src_idx/dst_idx: [2,000,000] int32.
//
// Round 14: dim-split with TRANSPOSED contiguous slices + non-temporal
// streaming -> per-XCD L2-resident gather.
//   mirror layout: xh[g][node][16 f16]  (8 slices x 3.2 MB contiguous)
//   aggregate block = (bucket b, dimgroup g=blockIdx&7): round-robin
//   dispatch parks g on XCD g; slice g (3.2MB) stays L2-resident; arena /
//   residual / out traffic is marked non-temporal so it can't evict it.
//   LDS f32 accum [128][17-stride] via ds_add, exact-64B-line writeout.

constexpr int DIM = 128;
constexpr int BSHIFT = 7;            // 128 nodes per bucket
constexpr int GNODES = 1 << BSHIFT;  // 128
constexpr int MAXB = 1024;           // max buckets (N <= 131072)
constexpr int CE = 8192;             // edges per partition chunk
constexpr int CAP_MAX = 3072;        // arena slots per bucket
constexpr int ASTRIDE = 17;          // padded LDS accum row stride

typedef float v4f __attribute__((ext_vector_type(4)));

__global__ void hgnn_fused_prep(const float4* __restrict__ x4,
                                ushort* __restrict__ xh, int nnodes,
                                const int* __restrict__ src,
                                const int* __restrict__ dst,
                                int* __restrict__ cursor,
                                int* __restrict__ arena, int cap,
                                int* __restrict__ spillCnt,
                                int2* __restrict__ spill, int spillCap,
                                int nedges, int nbk, int nPart) {
    __shared__ int h[MAXB];
    __shared__ int lb[MAXB];
    const int tid = threadIdx.x;

    if ((int)blockIdx.x < nPart) {
        // ---- partition path ----
        int c0 = blockIdx.x * CE;
        int c1 = min(c0 + CE, nedges);
        for (int i = tid; i < nbk; i += blockDim.x) h[i] = 0;
        __syncthreads();
        for (int i = c0 + tid; i < c1; i += blockDim.x)
            atomicAdd(&h[dst[i] >> BSHIFT], 1);
        __syncthreads();
        for (int i = tid; i < nbk; i += blockDim.x)
            lb[i] = h[i] ? atomicAdd(&cursor[i], h[i]) : 0;
        __syncthreads();
        for (int i = c0 + tid; i < c1; i += blockDim.x) {
            int s = src[i];
            int d = dst[i];
            int bk = d >> BSHIFT;
            int pos = atomicAdd(&lb[bk], 1);
            if (pos < cap) {
                arena[(size_t)bk * cap + pos] = s | ((d & (GNODES - 1)) << 17);
            } else {
                int sp = atomicAdd(spillCnt, 1);
                if (sp < spillCap) spill[sp] = make_int2(s, d);
            }
        }
    } else {
        // ---- convert path: x -> 8 contiguous f16 slices ----
        // work item k = (node, g): read 16 f32 (64B), write 16 f16 (32B)
        // slice write addr (ushort4 units): g*(nnodes*4) + node*4
        ushort4* xh4 = (ushort4*)xh;
        int bid = blockIdx.x - nPart;
        int nconv = gridDim.x - nPart;
        int i = bid * blockDim.x + tid;
        int stride = nconv * blockDim.x;
        int total = nnodes * 8;
        for (int k = i; k < total; k += stride) {
            int node = k >> 3;
            int g = k & 7;
            size_t rbase = (size_t)node * 32 + g * 4;
#pragma unroll
            for (int t = 0; t < 4; ++t) {
                float4 v = x4[rbase + t];
                ushort4 o;
                o.x = __half_as_ushort(__float2half_rn(v.x));
                o.y = __half_as_ushort(__float2half_rn(v.y));
                o.z = __half_as_ushort(__float2half_rn(v.z));
                o.w = __half_as_ushort(__float2half_rn(v.w));
                xh4[(size_t)g * nnodes * 4 + (size_t)node * 4 + t] = o;
            }
        }
    }
}

// block = (bucket b, dimgroup g). Edges of bucket b, dims [g*16, g*16+16).
// Slice gather (L2-resident) + LDS f32 accumulation; arena/residual/out
// traffic non-temporal.
__global__ void hgnn_aggregate_dsplit(const float* __restrict__ x,
                                      const uint4* __restrict__ xhT,
                                      const int* __restrict__ arena, int cap,
                                      const int* __restrict__ cursor,
                                      float* __restrict__ out, int nnodes) {
    __shared__ float accum[GNODES * ASTRIDE];   // 8704 B
    const int b = blockIdx.x >> 3;
    const int g = blockIdx.x & 7;      // aligns with XCD round-robin
    const int tid = threadIdx.x;

    for (int i = tid; i < GNODES * ASTRIDE; i += 256) accum[i] = 0.f;
    __syncthreads();

    int cnt = cursor[b];
    if (cnt > cap) cnt = cap;
    const int* ar = arena + (size_t)b * cap;
    // slice base in uint4 units: 32B/row = 2 uint4
    const uint4* slice = xhT + (size_t)g * nnodes * 2;

    // 2 lanes per edge; lane owns 16 B (8 f16 dims) of the 32 B slice row
    const int sub = tid & 1;
    for (int i = (tid >> 1); i < cnt; i += 128) {
        int p = __builtin_nontemporal_load(ar + i);
        int s = p & 0x1FFFF;
        int dl = p >> 17;
        uint4 v = slice[(size_t)s * 2 + sub];
        __half2 h0 = *reinterpret_cast<const __half2*>(&v.x);
        __half2 h1 = *reinterpret_cast<const __half2*>(&v.y);
        __half2 h2 = *reinterpret_cast<const __half2*>(&v.z);
        __half2 h3 = *reinterpret_cast<const __half2*>(&v.w);
        float2 f0 = __half22float2(h0);
        float2 f1 = __half22float2(h1);
        float2 f2 = __half22float2(h2);
        float2 f3 = __half22float2(h3);
        float* a = &accum[dl * ASTRIDE + sub * 8];
        atomicAdd(a + 0, f0.x);
        atomicAdd(a + 1, f0.y);
        atomicAdd(a + 2, f1.x);
        atomicAdd(a + 3, f1.y);
        atomicAdd(a + 4, f2.x);
        atomicAdd(a + 5, f2.y);
        atomicAdd(a + 6, f3.x);
        atomicAdd(a + 7, f3.y);
    }
    __syncthreads();

    // writeout: thread t -> node t>>1, half (t&1); 32 B per thread;
    // per (node,g): 64 B aligned line at out + node*512 + g*64
    {
        int r = tid >> 1;
        int half = tid & 1;
        int node = (b << BSHIFT) + r;
        if (node < nnodes) {
            size_t o = (size_t)node * DIM + g * 16 + half * 8;
            const float* a = &accum[r * ASTRIDE + half * 8];
            const v4f* xs = (const v4f*)(x + o);
            v4f xa = __builtin_nontemporal_load(xs);
            v4f xb = __builtin_nontemporal_load(xs + 1);
            v4f r0 = {xa.x + a[0], xa.y + a[1], xa.z + a[2], xa.w + a[3]};
            v4f r1 = {xb.x + a[4], xb.y + a[5], xb.z + a[6], xb.w + a[7]};
            __builtin_nontemporal_store(r0, (v4f*)(out + o));
            __builtin_nontemporal_store(r1, (v4f*)(out + o + 4));
        }
    }
}

// handles overflow edges (expected none on this data); exact f32 path
__global__ void hgnn_spill_apply(const float4* __restrict__ x4,
                                 const int* __restrict__ spillCnt,
                                 const int2* __restrict__ spill,
                                 float* __restrict__ out, int spillCap) {
    int n = *spillCnt;
    if (n > spillCap) n = spillCap;
    int i = blockIdx.x * blockDim.x + threadIdx.x;
    int stride = gridDim.x * blockDim.x;
    for (int k = i; k < n * 32; k += stride) {
        int e = k >> 5;
        int cc = k & 31;
        int2 sd = spill[e];
        float4 v = x4[(size_t)sd.x * 32 + cc];
        float* o = out + (size_t)sd.y * DIM + cc * 4;
        atomicAdd(o + 0, v.x);
        atomicAdd(o + 1, v.y);
        atomicAdd(o + 2, v.z);
        atomicAdd(o + 3, v.w);
    }
}

static inline size_t align256(size_t v) { return (v + 255) & ~(size_t)255; }

extern "C" void kernel_launch(void* const* d_in, const int* in_sizes, int n_in,
                              void* d_out, int out_size, void* d_ws, size_t ws_size,
                              hipStream_t stream) {
    const float* x = (const float*)d_in[0];
    const int* src = (const int*)d_in[1];
    const int* dst = (const int*)d_in[2];
    float* out = (float*)d_out;

    const int E = in_sizes[1];                   // 2,000,000
    const int N = in_sizes[0] / DIM;             // 100,000
    const int NBK = (N + GNODES - 1) >> BSHIFT;  // 782
    const int nPart = (E + CE - 1) / CE;         // 245 partition chunks

    // workspace: cursor[MAXB] + spillCnt | f16 sliced mirror | arena | spill
    char* w = (char*)d_ws;
    size_t curBytes = align256((size_t)(MAXB + 1) * sizeof(int));
    size_t xhBytes = align256((size_t)N * DIM * 2);   // 25.6 MB (8 slices)
    size_t fixedBytes = curBytes + xhBytes;
    size_t spillReserve = 256 * 1024;

    size_t avail = (ws_size > fixedBytes + spillReserve)
                       ? (ws_size - fixedBytes - spillReserve) : 0;
    int cap = (int)((avail / sizeof(int)) / (size_t)NBK);
    if (cap > CAP_MAX) cap = CAP_MAX;
    if (cap < 64) cap = 64;    // degenerate ws; spill net keeps correctness

    int* cursor = (int*)w;                        // [NBK]
    int* spillCnt = cursor + MAXB;                // [1]
    ushort* xh = (ushort*)(w + curBytes);         // 8 x [N][16] f16 slices
    int* arena = (int*)(w + fixedBytes);          // [NBK*cap]
    size_t arenaBytes = align256((size_t)NBK * cap * sizeof(int));
    int2* spill = (int2*)(w + fixedBytes + arenaBytes);
    int spillCap = (int)((ws_size > fixedBytes + arenaBytes)
                             ? (ws_size - fixedBytes - arenaBytes) / sizeof(int2)
                             : 0);

    // 1) zero cursors + spill counter
    (void)hipMemsetAsync(cursor, 0, (size_t)(MAXB + 1) * sizeof(int), stream);

    // 2) static fused: partition (blocks 0..nPart) || sliced f16 convert
    {
        int grid = nPart + 1792;
        hipLaunchKernelGGL(hgnn_fused_prep, dim3(grid), dim3(256), 0, stream,
                           (const float4*)x, xh, N,
                           src, dst, cursor, arena, cap,
                           spillCnt, spill, spillCap, E, NBK, nPart);
    }

    // 3) dim-split aggregate: 8 dimgroups x NBK buckets, g = blockIdx&7
    hipLaunchKernelGGL(hgnn_aggregate_dsplit, dim3(NBK * 8), dim3(256), 0, stream,
                       x, (const uint4*)xh, arena, cap, cursor, out, N);

    // 4) apply spilled edges (normally zero work)
    hipLaunchKernelGGL(hgnn_spill_apply, dim3(64), dim3(256), 0, stream,
                       (const float4*)x, spillCnt, spill, out, spillCap);
}

// Round 15
// 205.885 us; speedup vs baseline: 6.6087x; 6.6008x over previous
//
#include <hip/hip_runtime.h>
#include <hip/hip_fp16.h>

// HGNN aggregation: out = x + segment_sum(x[src_idx], dst_idx)
// x: [100000, 128] f32; src_idx/dst_idx: [2,000,000] int32.
//
// Round 15: L2-resident sliced gather (r14) + register accumulation (r12).
//   mirror: xh[g][node][16 f16], 8 contiguous 3.2MB slices (+ zero row N).
//   1. memset cursors
//   2. fused prep: partition -> per-bucket arenas || sliced f16 convert
//   3. refine: per-bucket LDS counting sort by node; arena becomes bare
//      src ids grouped by node; offsets[node] = local start. (~4M LDS
//      atomics total -- cheap; 256M per-element LDS atomics was the r13/r14
//      1.3ms disaster, never again)
//   4. aggregate: block=(bucket b, dimgroup g=blockIdx&7) -> XCD round-robin
//      parks slice g on XCD g (r14-proven: FETCH 94MB). 4 lanes/node own
//      4 dims each; 16 nodes/wave; 2-deep f16 register chains; no LDS;
//      exact-64B-line writeout with f32 residual.
//   5. spill_apply: f32 atomics for arena overflow (expected 0).

constexpr int DIM = 128;
constexpr int BSHIFT = 7;            // 128 nodes per bucket
constexpr int GNODES = 1 << BSHIFT;  // 128
constexpr int MAXB = 1024;           // max buckets (N <= 131072)
constexpr int CE = 8192;             // edges per partition chunk
constexpr int CAP_MAX = 3072;        // arena slots per bucket (mean 2558)

__global__ void hgnn_fused_prep(const float4* __restrict__ x4,
                                ushort4* __restrict__ xh4, int nnodes,
                                const int* __restrict__ src,
                                const int* __restrict__ dst,
                                int* __restrict__ cursor,
                                int* __restrict__ arena, int cap,
                                int* __restrict__ spillCnt,
                                int2* __restrict__ spill, int spillCap,
                                int nedges, int nbk, int nPart) {
    __shared__ int h[MAXB];
    __shared__ int lb[MAXB];
    const int tid = threadIdx.x;

    if ((int)blockIdx.x < nPart) {
        // ---- partition path ----
        int c0 = blockIdx.x * CE;
        int c1 = min(c0 + CE, nedges);
        for (int i = tid; i < nbk; i += blockDim.x) h[i] = 0;
        __syncthreads();
        for (int i = c0 + tid; i < c1; i += blockDim.x)
            atomicAdd(&h[dst[i] >> BSHIFT], 1);
        __syncthreads();
        for (int i = tid; i < nbk; i += blockDim.x)
            lb[i] = h[i] ? atomicAdd(&cursor[i], h[i]) : 0;
        __syncthreads();
        for (int i = c0 + tid; i < c1; i += blockDim.x) {
            int s = src[i];
            int d = dst[i];
            int bk = d >> BSHIFT;
            int pos = atomicAdd(&lb[bk], 1);
            if (pos < cap) {
                arena[(size_t)bk * cap + pos] = s | ((d & (GNODES - 1)) << 17);
            } else {
                int sp = atomicAdd(spillCnt, 1);
                if (sp < spillCap) spill[sp] = make_int2(s, d);
            }
        }
    } else {
        // ---- convert path: x -> 8 contiguous f16 slices, + zero row N ----
        // item k = (node, g); slice row = 16 f16 = 4 ushort4
        int bid = blockIdx.x - nPart;
        int nconv = gridDim.x - nPart;
        int i = bid * blockDim.x + tid;
        int stride = nconv * blockDim.x;
        int total = (nnodes + 1) * 8;
        int rowsPerSlice = nnodes + 1;
        for (int k = i; k < total; k += stride) {
            int node = k >> 3;
            int g = k & 7;
            ushort4* wp = xh4 + (size_t)g * rowsPerSlice * 4 + (size_t)node * 4;
            if (node == nnodes) {
                ushort4 z; z.x = 0; z.y = 0; z.z = 0; z.w = 0;
#pragma unroll
                for (int t = 0; t < 4; ++t) wp[t] = z;
            } else {
                size_t rbase = (size_t)node * 32 + g * 4;
#pragma unroll
                for (int t = 0; t < 4; ++t) {
                    float4 v = x4[rbase + t];
                    ushort4 o;
                    o.x = __half_as_ushort(__float2half_rn(v.x));
                    o.y = __half_as_ushort(__float2half_rn(v.y));
                    o.z = __half_as_ushort(__float2half_rn(v.z));
                    o.w = __half_as_ushort(__float2half_rn(v.w));
                    wp[t] = o;
                }
            }
        }
    }
}

// one block per bucket: LDS counting sort by local node id.
// arena entries become bare src ids, grouped by node; offsets[node] = local
// start of node's run (end = next node's start, or cnt for local node 127).
__global__ void hgnn_refine(int* __restrict__ arena, int cap,
                            const int* __restrict__ cursor,
                            int* __restrict__ offsets, int nnodes) {
    __shared__ int ebuf[CAP_MAX];
    __shared__ int hoff[GNODES + 1];
    __shared__ int cur[GNODES];
    const int b = blockIdx.x;
    const int tid = threadIdx.x;

    int cnt = cursor[b];
    if (cnt > cap) cnt = cap;
    int* ar = arena + (size_t)b * cap;

    for (int i = tid; i < GNODES; i += blockDim.x) cur[i] = 0;
    __syncthreads();
    for (int i = tid; i < cnt; i += blockDim.x) {
        int p = ar[i];
        ebuf[i] = p;
        atomicAdd(&cur[p >> 17], 1);
    }
    __syncthreads();

    // scan 128 counts -> hoff[0..128]
    int myc = (tid < GNODES) ? cur[tid] : 0;
    if (tid < GNODES) hoff[tid + 1] = myc;
    if (tid == 0) hoff[0] = 0;
    __syncthreads();
    for (int off = 1; off < GNODES; off <<= 1) {
        int v = (tid < GNODES && tid >= off) ? hoff[tid + 1 - off] : 0;
        __syncthreads();
        if (tid < GNODES) hoff[tid + 1] += v;
        __syncthreads();
    }
    if (tid < GNODES) cur[tid] = hoff[tid];
    __syncthreads();

    if (tid < GNODES) {
        int node = (b << BSHIFT) + tid;
        if (node < nnodes) offsets[node] = hoff[tid];
    }
    for (int i = tid; i < cnt; i += blockDim.x) {
        int p = ebuf[i];
        int pos = atomicAdd(&cur[p >> 17], 1);
        ar[pos] = p & 0x1FFFF;    // bare src id; node now implicit
    }
}

// block = (bucket b, dimgroup g). 4 lanes per node (4 dims each, uint2=8B),
// 16 nodes per wave, register f16 accumulation, no LDS.
__global__ void hgnn_aggregate_dsplit(const float4* __restrict__ x4,
                                      const uint2* __restrict__ xhT,
                                      const int* __restrict__ arena, int cap,
                                      const int* __restrict__ cursor,
                                      const int* __restrict__ offsets,
                                      float4* __restrict__ out4, int nnodes) {
    const int b = blockIdx.x >> 3;
    const int g = blockIdx.x & 7;      // aligns with XCD round-robin
    const int tid = threadIdx.x;
    const int sub = tid & 3;
    const int ZROW = nnodes;           // zeroed pad row per slice

    int cnt = cursor[b];
    if (cnt > cap) cnt = cap;
    const int* ar = arena + (size_t)b * cap;
    const uint2* slice = xhT + (size_t)g * (nnodes + 1) * 4;  // 4 uint2/row

    for (int pass = 0; pass < 2; ++pass) {
        int nr = pass * 64 + (tid >> 2);      // local node 0..127
        int node = (b << BSHIFT) + nr;
        if (node >= nnodes) break;

        int s0 = offsets[node];
        int e0 = (nr == GNODES - 1 || node + 1 >= nnodes) ? cnt
                                                          : offsets[node + 1];
        int m = e0 - s0;

        __half2 a0 = __floats2half2_rn(0.f, 0.f);
        __half2 a1 = a0, b0 = a0, b1 = a0;

        int j = 0;
        for (; j + 1 < m; j += 2) {           // 2 independent chains
            int p0 = ar[s0 + j];
            int p1 = ar[s0 + j + 1];
            uint2 v0 = slice[(size_t)p0 * 4 + sub];
            uint2 v1 = slice[(size_t)p1 * 4 + sub];
            a0 = __hadd2(a0, *reinterpret_cast<const __half2*>(&v0.x));
            a1 = __hadd2(a1, *reinterpret_cast<const __half2*>(&v0.y));
            b0 = __hadd2(b0, *reinterpret_cast<const __half2*>(&v1.x));
            b1 = __hadd2(b1, *reinterpret_cast<const __half2*>(&v1.y));
        }
        if (j < m) {
            int p0 = ar[s0 + j];
            uint2 v0 = slice[(size_t)p0 * 4 + sub];
            a0 = __hadd2(a0, *reinterpret_cast<const __half2*>(&v0.x));
            a1 = __hadd2(a1, *reinterpret_cast<const __half2*>(&v0.y));
        }
        (void)ZROW;

        __half2 slo = __hadd2(a0, b0);
        __half2 shi = __hadd2(a1, b1);
        float2 flo = __half22float2(slo);
        float2 fhi = __half22float2(shi);

        // out float4 index: node*32 + g*4 + sub -> 4 lanes = 64B line
        size_t o = (size_t)node * 32 + g * 4 + sub;
        float4 xv = x4[o];
        out4[o] = make_float4(xv.x + flo.x, xv.y + flo.y,
                              xv.z + fhi.x, xv.w + fhi.y);
    }
}

// handles arena-overflow edges (expected none on this data); exact f32 path
__global__ void hgnn_spill_apply(const float4* __restrict__ x4,
                                 const int* __restrict__ spillCnt,
                                 const int2* __restrict__ spill,
                                 float* __restrict__ out, int spillCap) {
    int n = *spillCnt;
    if (n > spillCap) n = spillCap;
    int i = blockIdx.x * blockDim.x + threadIdx.x;
    int stride = gridDim.x * blockDim.x;
    for (int k = i; k < n * 32; k += stride) {
        int e = k >> 5;
        int cc = k & 31;
        int2 sd = spill[e];
        float4 v = x4[(size_t)sd.x * 32 + cc];
        float* o = out + (size_t)sd.y * DIM + cc * 4;
        atomicAdd(o + 0, v.x);
        atomicAdd(o + 1, v.y);
        atomicAdd(o + 2, v.z);
        atomicAdd(o + 3, v.w);
    }
}

static inline size_t align256(size_t v) { return (v + 255) & ~(size_t)255; }

extern "C" void kernel_launch(void* const* d_in, const int* in_sizes, int n_in,
                              void* d_out, int out_size, void* d_ws, size_t ws_size,
                              hipStream_t stream) {
    const float* x = (const float*)d_in[0];
    const int* src = (const int*)d_in[1];
    const int* dst = (const int*)d_in[2];
    float* out = (float*)d_out;

    const int E = in_sizes[1];                   // 2,000,000
    const int N = in_sizes[0] / DIM;             // 100,000
    const int NBK = (N + GNODES - 1) >> BSHIFT;  // 782
    const int nPart = (E + CE - 1) / CE;         // 245 partition chunks

    // workspace: cursor[MAXB]+spillCnt | offsets[N] | sliced f16 mirror
    //            (8 x (N+1) rows) | arena | spill
    char* w = (char*)d_ws;
    size_t curBytes = align256((size_t)(MAXB + 1) * sizeof(int));
    size_t offBytes = align256((size_t)N * sizeof(int));
    size_t xhBytes = align256((size_t)(N + 1) * DIM * 2);
    size_t fixedBytes = curBytes + offBytes + xhBytes;
    size_t spillReserve = 256 * 1024;

    size_t avail = (ws_size > fixedBytes + spillReserve)
                       ? (ws_size - fixedBytes - spillReserve) : 0;
    int cap = (int)((avail / sizeof(int)) / (size_t)NBK);
    if (cap > CAP_MAX) cap = CAP_MAX;
    if (cap < 64) cap = 64;    // degenerate ws; spill net keeps correctness

    int* cursor = (int*)w;                            // [NBK]
    int* spillCnt = cursor + MAXB;                    // [1]
    int* offsets = (int*)(w + curBytes);              // [N] local starts
    ushort* xh = (ushort*)(w + curBytes + offBytes);  // 8 x [(N+1)][16] f16
    int* arena = (int*)(w + fixedBytes);              // [NBK*cap]
    size_t arenaBytes = align256((size_t)NBK * cap * sizeof(int));
    int2* spill = (int2*)(w + fixedBytes + arenaBytes);
    int spillCap = (int)((ws_size > fixedBytes + arenaBytes)
                             ? (ws_size - fixedBytes - arenaBytes) / sizeof(int2)
                             : 0);

    // 1) zero cursors + spill counter
    (void)hipMemsetAsync(cursor, 0, (size_t)(MAXB + 1) * sizeof(int), stream);

    // 2) fused: partition (blocks 0..nPart) || sliced f16 convert (rest)
    {
        int grid = nPart + 1792;
        hipLaunchKernelGGL(hgnn_fused_prep, dim3(grid), dim3(256), 0, stream,
                           (const float4*)x, (ushort4*)xh, N,
                           src, dst, cursor, arena, cap,
                           spillCnt, spill, spillCap, E, NBK, nPart);
    }

    // 3) per-bucket counting sort -> node-grouped bare src ids + offsets
    hipLaunchKernelGGL(hgnn_refine, dim3(NBK), dim3(256), 0, stream,
                       arena, cap, cursor, offsets, N);

    // 4) dim-split aggregate: 8 dimgroups x NBK buckets, g = blockIdx&7
    hipLaunchKernelGGL(hgnn_aggregate_dsplit, dim3(NBK * 8), dim3(256), 0,
                       stream, (const float4*)x, (const uint2*)xh, arena, cap,
                       cursor, offsets, (float4*)out, N);

    // 5) apply spilled edges (normally zero work)
    hipLaunchKernelGGL(hgnn_spill_apply, dim3(64), dim3(256), 0, stream,
                       (const float4*)x, spillCnt, spill, out, spillCap);
}